// Round 11
// baseline (95.122 us; speedup 1.0000x reference)
//
#include <hip/hip_runtime.h>

// RBF-MMD discriminator — R11 DIAGNOSTIC build.
// mmd compute time has been invariant (~22-26us) across 5 structures while
// issue models say 5-9us, and the 41us d_ws harness fills have hidden mmd's
// counter row every round. This build repeats the on-chip compute REPS=5x
// (rolled loop + compiler memory barrier; partials divided by REPS in f64
// finalize — exact) so mmd becomes the top dispatch and we finally get its
// VALUBusy/MfmaUtil/Occupancy/conflict counters, plus dur = fixed + 5*C
// separates fixed overhead from steady-state compute.
//
// Body = R8 (best, 71.8us, absmax 0.0): per-slab blocks, pure-bf16 dot via
// 16x16x32 MFMA, column norm folded into free K-slots (k16,k17 vs A=1.0),
// per-entry work = exp2 + add; row-scale 2^-g_row (+ weights) in epilogue.
// Kxx symmetry: strip-pairs q>=a only, q>a weighted 2x (exact).

#define LOG2E 1.4426950408889634f
#define SCALE 1.2011224087864498f   // sqrt(LOG2E)
#define NSLOT 26
#define ONEONE 0x3F803F80u          // packed bf16 {1.0, 1.0}
#define REPS 5

typedef __attribute__((ext_vector_type(8))) __bf16 bf16x8;
typedef __attribute__((ext_vector_type(4))) float floatx4;

union FragU { uint4 q; unsigned int u[4]; bf16x8 v; };

// 16B-aligned group-padded LDS row offset (dwords): 8 dw/row + 4 dw pad per 4 rows.
static __device__ __forceinline__ int off(int n) { return (n << 3) + ((n >> 2) << 2); }

static __device__ __forceinline__ unsigned short bfbits(__bf16 h) {
    union { __bf16 h; unsigned short s; } u; u.h = h; return u.s;
}
static __device__ __forceinline__ unsigned int packhh(__bf16 a, __bf16 b) {
    return (unsigned int)bfbits(a) | ((unsigned int)bfbits(b) << 16);
}
static __device__ __forceinline__ unsigned int packff(float a, float b) {
    return packhh((__bf16)(a * SCALE), (__bf16)(b * SCALE));
}

// grid (26,128): blockIdx.x = pair slot, blockIdx.y = t.
// slot<16: xy block, a=slot>>2 (A strip of X), q=slot&3 (col strip of Y).
// slot>=16: xx block over triangular (a,q), q>=a, weight 2 if q>a.
// 4 waves; wave w owns A rows a*128 + w*32 (two 16-row tiles).
__global__ __launch_bounds__(256, 8) void mmd_kernel(const float* __restrict__ x,
                                                     const float* __restrict__ y,
                                                     float* __restrict__ part) {
    __shared__ unsigned int AH[1152], BH[1152];
    __shared__ unsigned int BG[512];      // per B-row: {pack(-ghi,-glo),0,0,0}
    __shared__ float srg[128];            // g per A-row
    __shared__ unsigned int zero4[4];
    __shared__ float red[4];

    const int slot = blockIdx.x;
    const int t    = blockIdx.y;
    const int tid  = threadIdx.x;
    const int w    = tid >> 6;
    const int lane = tid & 63;
    const int quad = lane >> 4;
    const int l15  = lane & 15;
    const int qh   = quad & 1;

    int sa, sq, isxx;
    if (slot < 16) { isxx = 0; sa = slot >> 2; sq = slot & 3; }
    else {
        isxx = 1;
        const int s = slot - 16;
        if      (s < 4) { sa = 0; sq = s; }
        else if (s < 7) { sa = 1; sq = s - 3; }
        else if (s < 9) { sa = 2; sq = s - 5; }
        else            { sa = 3; sq = 3; }
    }

    if (tid == 0) { zero4[0] = 0u; zero4[1] = 0u; zero4[2] = 0u; zero4[3] = 0u; }

    // ---- staging: threads 0..127 convert A-rows (X), 128..255 B-rows ----
    {
        const int half = tid >> 7;
        const int r    = tid & 127;
        const float4* __restrict__ src4 =
            (half && !isxx) ? (const float4*)y : (const float4*)x;
        const size_t gb = (size_t)((half ? sq : sa) * 128 + r) * 512 + t * 4;
        float4 f0 = src4[gb], f1 = src4[gb + 1], f2 = src4[gb + 2], f3 = src4[gb + 3];
        const float g =
            (f0.x * f0.x + f0.y * f0.y + f0.z * f0.z + f0.w * f0.w) +
            (f1.x * f1.x + f1.y * f1.y + f1.z * f1.z + f1.w * f1.w) +
            (f2.x * f2.x + f2.y * f2.y + f2.z * f2.z + f2.w * f2.w) +
            (f3.x * f3.x + f3.y * f3.y + f3.z * f3.z + f3.w * f3.w);
        const unsigned int hw0 = packff(f0.x, f0.y);
        const unsigned int hw1 = packff(f0.z, f0.w);
        const unsigned int hw2 = packff(f1.x, f1.y);
        const unsigned int hw3 = packff(f1.z, f1.w);
        const unsigned int hw4 = packff(f2.x, f2.y);
        const unsigned int hw5 = packff(f2.z, f2.w);
        const unsigned int hw6 = packff(f3.x, f3.y);
        const unsigned int hw7 = packff(f3.z, f3.w);
        unsigned int* __restrict__ H = half ? BH : AH;
        const int o = off(r);
        *(uint4*)&H[o]     = make_uint4(hw0, hw1, hw2, hw3);
        *(uint4*)&H[o + 4] = make_uint4(hw4, hw5, hw6, hw7);
        const float gp = 0.5f * LOG2E * g;
        if (half) {
            const __bf16 nh = (__bf16)(-gp);
            const __bf16 nl = (__bf16)(-(gp + (float)nh));
            *(uint4*)&BG[r * 4] = make_uint4(packhh(nh, nl), 0u, 0u, 0u);
        } else {
            srg[r] = gp;
        }
    }
    __syncthreads();

    float wt = (t == 0 || t == 127) ? 1.f : 2.f;
    if (isxx && sq > sa) wt *= 2.f;   // symmetric off-diag strip-pair

    float tot = 0.f;

    // ===== DIAGNOSTIC: repeat on-chip compute REPS times (rolled) =====
#pragma unroll 1
    for (int rep = 0; rep < REPS; ++rep) {
        asm volatile("" ::: "memory");   // force LDS re-read; block hoisting

        // ---- A fragments for this rep ----
        bf16x8 a1f0, a1f1;
        {
            FragU u0, u1;
            if (quad < 2) {
                const int r0 = w * 32 + l15;
                u0.q = *(const uint4*)&AH[off(r0) + qh * 4];
                u1.q = *(const uint4*)&AH[off(r0 + 16) + qh * 4];
            } else {
                u0.q = make_uint4((quad == 2) ? ONEONE : 0u, 0u, 0u, 0u);
                u1.q = u0.q;
            }
            a1f0 = u0.v;
            a1f1 = u1.v;
        }

        // per-lane B-fragment pointer + per-jt stride (dwords)
        const unsigned int* bptr;
        int bstride;
        if (quad < 2)       { bptr = &BH[off(l15) + qh * 4]; bstride = 144; }
        else if (quad == 2) { bptr = &BG[l15 * 4];           bstride = 64;  }
        else                { bptr = &zero4[0];              bstride = 0;   }

        float s00 = 0.f, s01 = 0.f, s02 = 0.f, s03 = 0.f;
        float s10 = 0.f, s11 = 0.f, s12 = 0.f, s13 = 0.f;

        // ---- pipelined main loop: MFMA tile jt, exp tile jt-1 ----
        floatx4 accP0, accP1, accC0, accC1;
        {
            FragU b; b.q = *(const uint4*)bptr; bptr += bstride;
            floatx4 zc = {0.f, 0.f, 0.f, 0.f};
            accP0 = __builtin_amdgcn_mfma_f32_16x16x32_bf16(a1f0, b.v, zc, 0, 0, 0);
            accP1 = __builtin_amdgcn_mfma_f32_16x16x32_bf16(a1f1, b.v, zc, 0, 0, 0);
        }
#pragma unroll
        for (int jt = 1; jt < 8; ++jt) {
            FragU b; b.q = *(const uint4*)bptr; bptr += bstride;
            floatx4 zc = {0.f, 0.f, 0.f, 0.f};
            accC0 = __builtin_amdgcn_mfma_f32_16x16x32_bf16(a1f0, b.v, zc, 0, 0, 0);
            accC1 = __builtin_amdgcn_mfma_f32_16x16x32_bf16(a1f1, b.v, zc, 0, 0, 0);
            s00 += __builtin_amdgcn_exp2f(accP0[0]);
            s01 += __builtin_amdgcn_exp2f(accP0[1]);
            s02 += __builtin_amdgcn_exp2f(accP0[2]);
            s03 += __builtin_amdgcn_exp2f(accP0[3]);
            s10 += __builtin_amdgcn_exp2f(accP1[0]);
            s11 += __builtin_amdgcn_exp2f(accP1[1]);
            s12 += __builtin_amdgcn_exp2f(accP1[2]);
            s13 += __builtin_amdgcn_exp2f(accP1[3]);
            accP0 = accC0;
            accP1 = accC1;
        }
        s00 += __builtin_amdgcn_exp2f(accP0[0]);
        s01 += __builtin_amdgcn_exp2f(accP0[1]);
        s02 += __builtin_amdgcn_exp2f(accP0[2]);
        s03 += __builtin_amdgcn_exp2f(accP0[3]);
        s10 += __builtin_amdgcn_exp2f(accP1[0]);
        s11 += __builtin_amdgcn_exp2f(accP1[1]);
        s12 += __builtin_amdgcn_exp2f(accP1[2]);
        s13 += __builtin_amdgcn_exp2f(accP1[3]);

        // ---- epilogue: weighted row-scale into running total ----
        const int rbase = w * 32 + quad * 4;
        const float rs00 = wt * __builtin_amdgcn_exp2f(-srg[rbase + 0]);
        const float rs01 = wt * __builtin_amdgcn_exp2f(-srg[rbase + 1]);
        const float rs02 = wt * __builtin_amdgcn_exp2f(-srg[rbase + 2]);
        const float rs03 = wt * __builtin_amdgcn_exp2f(-srg[rbase + 3]);
        const float rs10 = wt * __builtin_amdgcn_exp2f(-srg[rbase + 16]);
        const float rs11 = wt * __builtin_amdgcn_exp2f(-srg[rbase + 17]);
        const float rs12 = wt * __builtin_amdgcn_exp2f(-srg[rbase + 18]);
        const float rs13 = wt * __builtin_amdgcn_exp2f(-srg[rbase + 19]);
        tot = fmaf(s00, rs00, tot); tot = fmaf(s01, rs01, tot);
        tot = fmaf(s02, rs02, tot); tot = fmaf(s03, rs03, tot);
        tot = fmaf(s10, rs10, tot); tot = fmaf(s11, rs11, tot);
        tot = fmaf(s12, rs12, tot); tot = fmaf(s13, rs13, tot);
    }

    // ---- block reduction, one store per block (sum is REPS x true) ----
    for (int o = 32; o > 0; o >>= 1) tot += __shfl_down(tot, o, 64);
    if (lane == 0) red[w] = tot;
    __syncthreads();
    if (tid == 0) {
        const int idx = isxx ? (2048 + t * 10 + (slot - 16)) : (t * 16 + slot);
        part[idx] = red[0] + red[1] + red[2] + red[3];
    }
}

__global__ __launch_bounds__(256) void finalize_kernel(const float* __restrict__ part,
                                                       float* __restrict__ out) {
    const int tid = threadIdx.x;
    double vxy = 0.0, vxx = 0.0;
#pragma unroll
    for (int k = 0; k < 8; ++k)  vxy += (double)part[tid + 256 * k];      // [0,2048)
#pragma unroll
    for (int k = 8; k < 13; ++k) vxx += (double)part[tid + 256 * k];      // [2048,3328)
    for (int o = 32; o > 0; o >>= 1) {
        vxx += __shfl_down(vxx, o, 64);
        vxy += __shfl_down(vxy, o, 64);
    }
    __shared__ double red[8];
    const int wid = tid >> 6;
    if ((tid & 63) == 0) { red[wid] = vxx; red[4 + wid] = vxy; }
    __syncthreads();
    if (tid == 0) {
        // sums are REPS x true: divide first, then subtract the diagonal
        double sxx = (red[0] + red[1] + red[2] + red[3]) / (double)REPS;
        double sxy = (red[4] + red[5] + red[6] + red[7]) / (double)REPS;
        double e1 = (sxx - 254.0 * 512.0) / (254.0 * 512.0 * 511.0);
        double e2 = sxy / (254.0 * 512.0 * 512.0);
        out[0] = (float)(e1 - 2.0 * e2);
    }
}

extern "C" void kernel_launch(void* const* d_in, const int* in_sizes, int n_in,
                              void* d_out, int out_size, void* d_ws, size_t ws_size,
                              hipStream_t stream) {
    (void)in_sizes; (void)n_in; (void)out_size; (void)ws_size;
    const float* x = (const float*)d_in[0];
    const float* y = (const float*)d_in[1];
    float* out  = (float*)d_out;
    float* part = (float*)d_ws;   // 3328 floats: [0,2048) xy, [2048,3328) xx

    mmd_kernel<<<dim3(NSLOT, 128), dim3(256), 0, stream>>>(x, y, part);
    finalize_kernel<<<dim3(1), dim3(256), 0, stream>>>(part, out);
}

// Round 12
// 72.815 us; speedup vs baseline: 1.3063x; 1.3063x over previous
//
#include <hip/hip_runtime.h>

// RBF-MMD discriminator: B=512 rows, T=128 slabs, C=16, fp32.
// out = E_xx - 2*E_xy over per-slab RBF grams (slab weight 1 for t in {0,127},
// else 2; 254 weighted slab instances).
//
// R12 structure: R11's REPS diagnostic decomposed mmd: compute ~6us (exp2
// throughput, matches model) + ~18us per-block fixed cost (staging latency/
// barrier/ramp) paid 3328x. Fix the RATIO: block = (t, A-half, B-half) stages
// 512 rows and computes a 256x256 gram quarter -> 896 blocks (fixed ÷3.7),
// B-frag reuse 4x, grid fully co-resident (~3.5 blocks/CU).
//
// Numerics = R8/R11 (absmax 0.0): pure-bf16 dot via 16x16x32 MFMA, column
// norm folded into free K-slots (k16,k17 = -g_col hi/lo vs A=1.0 consts),
// acc = log2e*(dot - |col|^2/2); per-entry work = exp2 + add.
// Row-scale 2^-g_row (+ slab weight) in epilogue; diagonal subtracted in
// finalize. Kxx symmetry: half-pairs (0,0),(0,1),(1,1); (0,1) weighted 2x.

#define LOG2E 1.4426950408889634f
#define SCALE 1.2011224087864498f   // sqrt(LOG2E)
#define ONEONE 0x3F803F80u          // packed bf16 {1.0, 1.0}

typedef __attribute__((ext_vector_type(8))) __bf16 bf16x8;
typedef __attribute__((ext_vector_type(4))) float floatx4;

union FragU { uint4 q; unsigned int u[4]; bf16x8 v; };

// 16B-aligned group-padded LDS row offset (dwords): 8 dw/row + 4 dw pad per 4 rows.
static __device__ __forceinline__ int off(int n) { return (n << 3) + ((n >> 2) << 2); }

static __device__ __forceinline__ unsigned short bfbits(__bf16 h) {
    union { __bf16 h; unsigned short s; } u; u.h = h; return u.s;
}
static __device__ __forceinline__ unsigned int packhh(__bf16 a, __bf16 b) {
    return (unsigned int)bfbits(a) | ((unsigned int)bfbits(b) << 16);
}
static __device__ __forceinline__ unsigned int packff(float a, float b) {
    return packhh((__bf16)(a * SCALE), (__bf16)(b * SCALE));
}

// grid (7,128): blockIdx.x = pair slot, blockIdx.y = t.
// slot 0..3: xy, Ah=slot>>1 (X half), Bh=slot&1 (Y half).
// slot 4..6: xx half-pairs (0,0),(0,1),(1,1); (0,1) weighted 2x (symmetry).
// 4 waves; wave w owns A rows w*64..w*64+63 (four 16-row MFMA tiles).
__global__ __launch_bounds__(256, 4) void mmd_kernel(const float* __restrict__ x,
                                                     const float* __restrict__ y,
                                                     float* __restrict__ part) {
    __shared__ unsigned int AH[2300], BH[2300];
    __shared__ unsigned int BG[1024];     // per B-row: {pack(-ghi,-glo),0,0,0}
    __shared__ float srg[256];            // g per A-row
    __shared__ unsigned int zero4[4];
    __shared__ float red[4];

    const int slot = blockIdx.x;
    const int t    = blockIdx.y;
    const int tid  = threadIdx.x;
    const int w    = tid >> 6;
    const int lane = tid & 63;
    const int quad = lane >> 4;
    const int l15  = lane & 15;
    const int qh   = quad & 1;

    int Ah, Bh, isxx;
    if (slot < 4) { isxx = 0; Ah = slot >> 1; Bh = slot & 1; }
    else {
        isxx = 1;
        Ah = (slot == 6) ? 1 : 0;          // (0,0),(0,1),(1,1)
        Bh = (slot == 4) ? 0 : 1;
    }

    if (tid == 0) { zero4[0] = 0u; zero4[1] = 0u; zero4[2] = 0u; zero4[3] = 0u; }

    // ---- staging: every thread converts one A-row (X) and one B-row ----
    {
        const float4* __restrict__ xa = (const float4*)x;
        const float4* __restrict__ bsrc = isxx ? (const float4*)x : (const float4*)y;
        const size_t ga = (size_t)(Ah * 256 + tid) * 512 + t * 4;
        const size_t gbb = (size_t)(Bh * 256 + tid) * 512 + t * 4;
        float4 a0 = xa[ga], a1 = xa[ga + 1], a2 = xa[ga + 2], a3 = xa[ga + 3];
        float4 b0 = bsrc[gbb], b1 = bsrc[gbb + 1], b2 = bsrc[gbb + 2], b3 = bsrc[gbb + 3];

        const float gA =
            (a0.x * a0.x + a0.y * a0.y + a0.z * a0.z + a0.w * a0.w) +
            (a1.x * a1.x + a1.y * a1.y + a1.z * a1.z + a1.w * a1.w) +
            (a2.x * a2.x + a2.y * a2.y + a2.z * a2.z + a2.w * a2.w) +
            (a3.x * a3.x + a3.y * a3.y + a3.z * a3.z + a3.w * a3.w);
        const float gB =
            (b0.x * b0.x + b0.y * b0.y + b0.z * b0.z + b0.w * b0.w) +
            (b1.x * b1.x + b1.y * b1.y + b1.z * b1.z + b1.w * b1.w) +
            (b2.x * b2.x + b2.y * b2.y + b2.z * b2.z + b2.w * b2.w) +
            (b3.x * b3.x + b3.y * b3.y + b3.z * b3.z + b3.w * b3.w);

        const int o = off(tid);
        *(uint4*)&AH[o]     = make_uint4(packff(a0.x, a0.y), packff(a0.z, a0.w),
                                         packff(a1.x, a1.y), packff(a1.z, a1.w));
        *(uint4*)&AH[o + 4] = make_uint4(packff(a2.x, a2.y), packff(a2.z, a2.w),
                                         packff(a3.x, a3.y), packff(a3.z, a3.w));
        *(uint4*)&BH[o]     = make_uint4(packff(b0.x, b0.y), packff(b0.z, b0.w),
                                         packff(b1.x, b1.y), packff(b1.z, b1.w));
        *(uint4*)&BH[o + 4] = make_uint4(packff(b2.x, b2.y), packff(b2.z, b2.w),
                                         packff(b3.x, b3.y), packff(b3.z, b3.w));
        srg[tid] = 0.5f * LOG2E * gA;
        const float gp = 0.5f * LOG2E * gB;
        const __bf16 nh = (__bf16)(-gp);
        const __bf16 nl = (__bf16)(-(gp + (float)nh));
        *(uint4*)&BG[tid * 4] = make_uint4(packhh(nh, nl), 0u, 0u, 0u);
    }
    __syncthreads();

    // ---- A fragments: 4 row-tiles per wave ----
    bf16x8 a1f0, a1f1, a1f2, a1f3;
    {
        FragU u0, u1, u2, u3;
        if (quad < 2) {
            const int r0 = w * 64 + l15;
            u0.q = *(const uint4*)&AH[off(r0) + qh * 4];
            u1.q = *(const uint4*)&AH[off(r0 + 16) + qh * 4];
            u2.q = *(const uint4*)&AH[off(r0 + 32) + qh * 4];
            u3.q = *(const uint4*)&AH[off(r0 + 48) + qh * 4];
        } else {
            u0.q = make_uint4((quad == 2) ? ONEONE : 0u, 0u, 0u, 0u);
            u1.q = u0.q; u2.q = u0.q; u3.q = u0.q;
        }
        a1f0 = u0.v; a1f1 = u1.v; a1f2 = u2.v; a1f3 = u3.v;
    }

    // per-lane B-fragment pointer + per-jt stride (dwords)
    const unsigned int* bptr;
    int bstride;
    if (quad < 2)       { bptr = &BH[off(l15) + qh * 4]; bstride = 144; }
    else if (quad == 2) { bptr = &BG[l15 * 4];           bstride = 64;  }
    else                { bptr = &zero4[0];              bstride = 0;   }

    float s0[4] = {0.f, 0.f, 0.f, 0.f};
    float s1[4] = {0.f, 0.f, 0.f, 0.f};
    float s2[4] = {0.f, 0.f, 0.f, 0.f};
    float s3[4] = {0.f, 0.f, 0.f, 0.f};

    // ---- pipelined main loop over 16 j-tiles: MFMA tile jt, exp tile jt-1 ----
    floatx4 p0, p1, p2, p3, c0, c1, c2, c3;
    {
        FragU b; b.q = *(const uint4*)bptr; bptr += bstride;
        floatx4 zc = {0.f, 0.f, 0.f, 0.f};
        p0 = __builtin_amdgcn_mfma_f32_16x16x32_bf16(a1f0, b.v, zc, 0, 0, 0);
        p1 = __builtin_amdgcn_mfma_f32_16x16x32_bf16(a1f1, b.v, zc, 0, 0, 0);
        p2 = __builtin_amdgcn_mfma_f32_16x16x32_bf16(a1f2, b.v, zc, 0, 0, 0);
        p3 = __builtin_amdgcn_mfma_f32_16x16x32_bf16(a1f3, b.v, zc, 0, 0, 0);
    }
#pragma unroll
    for (int jt = 1; jt < 16; ++jt) {
        FragU b; b.q = *(const uint4*)bptr; bptr += bstride;
        floatx4 zc = {0.f, 0.f, 0.f, 0.f};
        c0 = __builtin_amdgcn_mfma_f32_16x16x32_bf16(a1f0, b.v, zc, 0, 0, 0);
        c1 = __builtin_amdgcn_mfma_f32_16x16x32_bf16(a1f1, b.v, zc, 0, 0, 0);
        c2 = __builtin_amdgcn_mfma_f32_16x16x32_bf16(a1f2, b.v, zc, 0, 0, 0);
        c3 = __builtin_amdgcn_mfma_f32_16x16x32_bf16(a1f3, b.v, zc, 0, 0, 0);
#pragma unroll
        for (int r = 0; r < 4; ++r) {
            s0[r] += __builtin_amdgcn_exp2f(p0[r]);
            s1[r] += __builtin_amdgcn_exp2f(p1[r]);
            s2[r] += __builtin_amdgcn_exp2f(p2[r]);
            s3[r] += __builtin_amdgcn_exp2f(p3[r]);
        }
        p0 = c0; p1 = c1; p2 = c2; p3 = c3;
    }
#pragma unroll
    for (int r = 0; r < 4; ++r) {
        s0[r] += __builtin_amdgcn_exp2f(p0[r]);
        s1[r] += __builtin_amdgcn_exp2f(p1[r]);
        s2[r] += __builtin_amdgcn_exp2f(p2[r]);
        s3[r] += __builtin_amdgcn_exp2f(p3[r]);
    }

    // ---- epilogue: weighted row-scale into running total ----
    float wt = (t == 0 || t == 127) ? 1.f : 2.f;
    if (slot == 5) wt *= 2.f;   // xx (0,1) also covers (1,0)
    float tot = 0.f;
    const int rbase = w * 64 + quad * 4;
#pragma unroll
    for (int r = 0; r < 4; ++r) {
        tot = fmaf(s0[r], wt * __builtin_amdgcn_exp2f(-srg[rbase + r]),      tot);
        tot = fmaf(s1[r], wt * __builtin_amdgcn_exp2f(-srg[rbase + 16 + r]), tot);
        tot = fmaf(s2[r], wt * __builtin_amdgcn_exp2f(-srg[rbase + 32 + r]), tot);
        tot = fmaf(s3[r], wt * __builtin_amdgcn_exp2f(-srg[rbase + 48 + r]), tot);
    }

    // ---- block reduction, one store per block ----
    for (int o = 32; o > 0; o >>= 1) tot += __shfl_down(tot, o, 64);
    if (lane == 0) red[w] = tot;
    __syncthreads();
    if (tid == 0) {
        // layout: xy -> [0,512) at t*4+slot; xx -> [512,896) at 512 + t*3 + slot-4
        const int idx = isxx ? (512 + t * 3 + (slot - 4)) : (t * 4 + slot);
        part[idx] = red[0] + red[1] + red[2] + red[3];
    }
}

__global__ __launch_bounds__(256) void finalize_kernel(const float* __restrict__ part,
                                                       float* __restrict__ out) {
    const int tid = threadIdx.x;
    double vxy = (double)part[tid] + (double)part[256 + tid];   // [0,512)
    double vxx = (double)part[512 + tid];                        // [512,768)
    if (tid < 128) vxx += (double)part[768 + tid];               // [768,896)
    for (int o = 32; o > 0; o >>= 1) {
        vxx += __shfl_down(vxx, o, 64);
        vxy += __shfl_down(vxy, o, 64);
    }
    __shared__ double red[8];
    const int wid = tid >> 6;
    if ((tid & 63) == 0) { red[wid] = vxx; red[4 + wid] = vxy; }
    __syncthreads();
    if (tid == 0) {
        double sxx = red[0] + red[1] + red[2] + red[3];
        double sxy = red[4] + red[5] + red[6] + red[7];
        // diagonal entries (~1.0 each) included in sxx: subtract 254*512
        double e1 = (sxx - 254.0 * 512.0) / (254.0 * 512.0 * 511.0);
        double e2 = sxy / (254.0 * 512.0 * 512.0);
        out[0] = (float)(e1 - 2.0 * e2);
    }
}

extern "C" void kernel_launch(void* const* d_in, const int* in_sizes, int n_in,
                              void* d_out, int out_size, void* d_ws, size_t ws_size,
                              hipStream_t stream) {
    (void)in_sizes; (void)n_in; (void)out_size; (void)ws_size;
    const float* x = (const float*)d_in[0];
    const float* y = (const float*)d_in[1];
    float* out  = (float*)d_out;
    float* part = (float*)d_ws;   // 896 floats: [0,512) xy, [512,896) xx

    mmd_kernel<<<dim3(7, 128), dim3(256), 0, stream>>>(x, y, part);
    finalize_kernel<<<dim3(1), dim3(256), 0, stream>>>(part, out);
}